// Round 14
// baseline (69.588 us; speedup 1.0000x reference)
//
#include <hip/hip_runtime.h>
#include <cstdint>

typedef __attribute__((ext_vector_type(4))) int   i32x4;
typedef __attribute__((ext_vector_type(2))) float f32x2;

#define XROWS  22
#define ROWB   2048              // LDS bytes per staged row (w 0..31, 64B each)
#define WSLICE 8192
#define WB_BYTES 409600          // wb (401408) rounded up
#define XT_BYTES ((size_t)16 * 112 * 128 * 64)
#define GRID_MAIN 1536           // 2 exact layers at 3 blocks/CU; 128 blocks run a quarter-tile pass 2

__device__ __forceinline__ void g2lds16(const void* g, void* l) {
  __builtin_amdgcn_global_load_lds(
      (const __attribute__((address_space(1))) unsigned int*)g,
      (__attribute__((address_space(3))) unsigned int*)l, 16, 0, 0);
}

// ---- standalone W pack (fallback path): wb[((s*4+g)*128+co)*16+lo], s=kh*7+kw
__global__ void prep_w(const float* __restrict__ w1,
                       const float* __restrict__ w2,
                       const float* __restrict__ w3,
                       signed char* __restrict__ wb) {
  int t = blockIdx.x * 256 + threadIdx.x;
  int lo = t & 15;
  int co = (t >> 4) & 127;
  int g  = (t >> 11) & 3;
  int s  = t >> 13;
  if (s >= 49) return;
  int kh = s / 7, kw = s % 7;
  int ci = g * 16 + lo;
  int base = ((co * 64 + ci) * 7 + kh) * 3;
  float v;
  if (kw < 3)       v = w1[base + kw];
  else if (kw == 3) v = w2[base + 1];
  else              v = w3[base + kw - 4];
  wb[t] = (signed char)(int)v;
}

// ---- merged prep: X pre-transpose + W pack (16x16 layout).
// xt[n][h][w(128)][ci(64)] i8, clamped, 16B-granule-swizzled (granule p holds
// ci-granule p ^ ((w>>1)&3)).
__global__ void prep_xw(const int* __restrict__ x,
                        const float* __restrict__ w1,
                        const float* __restrict__ w2,
                        const float* __restrict__ w3,
                        signed char* __restrict__ xt,
                        signed char* __restrict__ wb) {
  __shared__ unsigned char T[64 * 68];
  const int tid = threadIdx.x;
  const int wt = blockIdx.x * 64, h = blockIdx.y, n = blockIdx.z;
  const int fid = (blockIdx.z * 112 + blockIdx.y) * 2 + blockIdx.x;

  if (fid < 1568) {                              // W pack: 1568*256 = 401408 elems
    int t = fid * 256 + tid;
    int lo = t & 15;
    int co = (t >> 4) & 127;
    int g  = (t >> 11) & 3;
    int s  = t >> 13;
    int kh = s / 7, kw = s % 7;
    int ci = g * 16 + lo;
    int base = ((co * 64 + ci) * 7 + kh) * 3;
    float v;
    if (kw < 3)       v = w1[base + kw];
    else if (kw == 3) v = w2[base + 1];
    else              v = w3[base + kw - 4];
    wb[t] = (signed char)(int)v;
  }

  {
    const int wr = tid & 63;
    const int cb = (tid >> 6) * 16;
    int ws = wt + wr; ws = ws < 112 ? ws : 111;
    const int* xp = x + (((size_t)n * 64 + cb) * 112 + h) * 112 + ws;
    #pragma unroll
    for (int g4 = 0; g4 < 4; ++g4) {
      uint32_t v = 0;
      #pragma unroll
      for (int j = 0; j < 4; ++j) {
        int a = xp[(g4 * 4 + j) * 12544];
        a = a < 0 ? 0 : (a > 7 ? 7 : a);
        v |= (uint32_t)a << (8 * j);
      }
      *(uint32_t*)&T[wr * 68 + cb + g4 * 4] = v;
    }
  }
  __syncthreads();
  {
    const int wo = tid >> 2, q = tid & 3;
    const int key = ((wt + wo) >> 1) & 3;
    const int sg = (q ^ key) << 4;
    int4 v;
    v.x = *(const int*)&T[wo * 68 + sg + 0];
    v.y = *(const int*)&T[wo * 68 + sg + 4];
    v.z = *(const int*)&T[wo * 68 + sg + 8];
    v.w = *(const int*)&T[wo * 68 + sg + 12];
    *(int4*)&xt[(((size_t)n * 112 + h) * 128 + wt + wo) * 64 + q * 16] = v;
  }
}

// Operand-swapped MFMA: A = X-frag (M = wo), B = W-frag (N = co).
// Exactness: both operands' effective k-granule is lkg (xt pre-swizzle ^ read
// swizzle cancel), and A/B per-lane layouts are symmetric.
#define MFMAX(acc, xf, wf) acc = __builtin_amdgcn_mfma_i32_16x16x64_i8(xf, wf, acc, 0, 0, 0)
#define MFMA16(acc, a, b)  acc = __builtin_amdgcn_mfma_i32_16x16x64_i8(a, b, acc, 0, 0, 0)

// One kw column: 16 B-ring reads, 7 kh batches of 16 MFMA.
// A-ring slot = (kh + PHASE) % 3, PHASE = position-in-sequence % 3.
template<int PHASE>
__device__ __forceinline__ void kw_body(const int kw,
    const signed char* __restrict__ aB, const unsigned char* Xs,
    const int lrow, const int lkg,
    i32x4& A0, i32x4& A1, i32x4& A2, i32x4 (&acc)[16]) {
  const int w_l  = lrow + kw;
  const int bcol = w_l * 64 + ((lkg ^ ((w_l >> 1) & 3)) << 4);
  i32x4 B[16];                             // ring: slot r&15 holds row r
  #pragma unroll
  for (int b = 0; b < 16; ++b)
    B[b] = *(const i32x4*)&Xs[b * ROWB + bcol];

  #pragma unroll
  for (int kh = 0; kh < 7; ++kh) {
    const int nkh = (kh <= 3) ? kh + 3 : kh - 4;
    const int nkw = (kh <= 3) ? kw : (kw == 6 ? 0 : kw + 1);
    const signed char* apn = aB + (size_t)(nkh * 7 + nkw) * WSLICE;
    __builtin_amdgcn_s_setprio(1);
    if (((kh + PHASE) % 3) == 0) {
      MFMAX(acc[0], B[kh], A0);                    // j=0: last consumer of slot kh
      if (kh < 6) B[kh] = *(const i32x4*)&Xs[(kh + 16) * ROWB + bcol];
      #pragma unroll
      for (int j = 1; j < 16; ++j) MFMAX(acc[j], B[(kh + j) & 15], A0);
      __builtin_amdgcn_s_setprio(0);
      A0 = *(const i32x4*)apn;
    } else if (((kh + PHASE) % 3) == 1) {
      MFMAX(acc[0], B[kh], A1);
      if (kh < 6) B[kh] = *(const i32x4*)&Xs[(kh + 16) * ROWB + bcol];
      #pragma unroll
      for (int j = 1; j < 16; ++j) MFMAX(acc[j], B[(kh + j) & 15], A1);
      __builtin_amdgcn_s_setprio(0);
      A1 = *(const i32x4*)apn;
    } else {
      MFMAX(acc[0], B[kh], A2);
      if (kh < 6) B[kh] = *(const i32x4*)&Xs[(kh + 16) * ROWB + bcol];
      #pragma unroll
      for (int j = 1; j < 16; ++j) MFMAX(acc[j], B[(kh + j) & 15], A2);
      __builtin_amdgcn_s_setprio(0);
      A2 = *(const i32x4*)apn;
    }
  }
}

// Quarter-tile column (pass 2 tail): 4 ho rows, B[10] flat, A-ring-3.
template<int PHASE>
__device__ __forceinline__ void kw_body_q(const int kw,
    const signed char* __restrict__ aB, const unsigned char* Xs,
    const int lrow, const int lkg,
    i32x4& A0, i32x4& A1, i32x4& A2, i32x4 (&acc)[4]) {
  const int w_l  = lrow + kw;
  const int bcol = w_l * 64 + ((lkg ^ ((w_l >> 1) & 3)) << 4);
  i32x4 B[10];
  #pragma unroll
  for (int b = 0; b < 10; ++b)
    B[b] = *(const i32x4*)&Xs[b * ROWB + bcol];
  #pragma unroll
  for (int kh = 0; kh < 7; ++kh) {
    const int nkh = (kh <= 3) ? kh + 3 : kh - 4;
    const int nkw = (kh <= 3) ? kw : (kw == 6 ? 0 : kw + 1);
    const signed char* apn = aB + (size_t)(nkh * 7 + nkw) * WSLICE;
    if (((kh + PHASE) % 3) == 0) {
      #pragma unroll
      for (int j = 0; j < 4; ++j) MFMAX(acc[j], B[kh + j], A0);
      A0 = *(const i32x4*)apn;
    } else if (((kh + PHASE) % 3) == 1) {
      #pragma unroll
      for (int j = 0; j < 4; ++j) MFMAX(acc[j], B[kh + j], A1);
      A1 = *(const i32x4*)apn;
    } else {
      #pragma unroll
      for (int j = 0; j < 4; ++j) MFMAX(acc[j], B[kh + j], A2);
      A2 = *(const i32x4*)apn;
    }
  }
}

// ---- main conv: static grid 1536; blocks 0..127 run one ho-quarter of the
// 32 leftover tiles as pass 2 (tail runs 128-wide instead of 32-solo).
// Wave = co16 x ho16 x wo16; swapped-operand epilogue: row=wo -> f32x2 stores.
__global__ __launch_bounds__(256, 3)
void conv7s(const signed char* __restrict__ xt,
            const signed char* __restrict__ wb,
            float* __restrict__ out) {
  __shared__ __align__(16) unsigned char Xs[XROWS * ROWB];   // 45056 B

  const int tid  = threadIdx.x;
  const int lane = tid & 63;
  const int wid  = tid >> 6;               // wave = co16 quarter of co64
  const int lrow = lane & 15;
  const int lkg  = lane >> 4;

  // bijective XCD chunking: 1536 = 8 * 192
  const int L  = blockIdx.x;
  const int Lp = (L & 7) * 192 + (L >> 3);

  // rotated kw sequence (kept from R13; any order exact for int accum)
  const int k0 = (L >> 3) % 7;
  const int k1 = (k0 + 1) % 7;
  const int k2 = (k0 + 2) % 7;
  const int k3 = (k0 + 3) % 7;
  const int k4 = (k0 + 4) % 7;
  const int k5 = (k0 + 5) % 7;
  const int k6 = (k0 + 6) % 7;

  // ================= pass 1: full tile =================
  {
    const int t = Lp;
    const int coh = t & 1;
    const int r2  = t >> 1;
    const int bx  = r2 % 7;
    const int t7  = r2 / 7;
    const int by  = t7 % 7;
    const int n   = t7 / 7;
    const int ho_base = by * 16;
    const int wo_base = bx * 16;

    const signed char* aB = wb + lkg * 2048 + (coh * 64 + wid * 16 + lrow) * 16;

    i32x4 A0 = *(const i32x4*)(aB + (size_t)(0 * 7 + k0) * WSLICE);
    i32x4 A1 = *(const i32x4*)(aB + (size_t)(1 * 7 + k0) * WSLICE);
    i32x4 A2 = *(const i32x4*)(aB + (size_t)(2 * 7 + k0) * WSLICE);

    for (int r = wid; r < XROWS; r += 4) {
      int h = ho_base + r; h = h < 112 ? h : 111;   // clamped rows feed only masked outputs
      const signed char* src = xt + (((size_t)n * 112 + h) * 128 + wo_base) * 64;
      g2lds16(src + lane * 16, &Xs[r * ROWB]);
      g2lds16(src + 1024 + lane * 16, &Xs[r * ROWB + 1024]);
    }
    asm volatile("s_waitcnt vmcnt(0)" ::: "memory");
    __syncthreads();

    i32x4 acc[16];
    #pragma unroll
    for (int j = 0; j < 16; ++j) acc[j] = (i32x4){0, 0, 0, 0};

    kw_body<0>(k0, aB, Xs, lrow, lkg, A0, A1, A2, acc);
    kw_body<1>(k1, aB, Xs, lrow, lkg, A0, A1, A2, acc);
    kw_body<2>(k2, aB, Xs, lrow, lkg, A0, A1, A2, acc);
    kw_body<0>(k3, aB, Xs, lrow, lkg, A0, A1, A2, acc);
    kw_body<1>(k4, aB, Xs, lrow, lkg, A0, A1, A2, acc);
    kw_body<2>(k5, aB, Xs, lrow, lkg, A0, A1, A2, acc);
    kw_body<0>(k6, aB, Xs, lrow, lkg, A0, A1, A2, acc);

    // epilogue (swapped map): col=lane&15 -> co, row=(lane>>4)*4+jj -> wo
    const int co  = coh * 64 + wid * 16 + lrow;
    const int wo0 = wo_base + lkg * 4;
    const bool full4 = (wo0 + 3) < 106;
    #pragma unroll
    for (int j = 0; j < 16; ++j) {
      const int ho = ho_base + j;
      if (ho < 106) {
        float* op = out + (((size_t)n * 128 + co) * 106 + ho) * 106 + wo0;
        if (full4) {                        // row start even, wo0 even -> 8B aligned
          *(f32x2*)(op)     = (f32x2){(float)acc[j][0], (float)acc[j][1]};
          *(f32x2*)(op + 2) = (f32x2){(float)acc[j][2], (float)acc[j][3]};
        } else {
          #pragma unroll
          for (int jj = 0; jj < 4; ++jj)
            if (wo0 + jj < 106) op[jj] = (float)acc[j][jj];
        }
      }
    }
  }

  // ================= pass 2: quarter tile (tail) =================
  if (L < 128) {
    const int t = GRID_MAIN + (L >> 2);    // tiles 1536..1567
    const int q = L & 3;                   // ho quarter
    const int coh = t & 1;
    const int r2  = t >> 1;
    const int bx  = r2 % 7;
    const int t7  = r2 / 7;
    const int by  = t7 % 7;
    const int n   = t7 / 7;
    const int hob2    = by * 16 + q * 4;
    const int wo_base = bx * 16;

    const signed char* aB = wb + lkg * 2048 + (coh * 64 + wid * 16 + lrow) * 16;

    __syncthreads();                       // protect Xs reuse
    for (int r = wid; r < 10; r += 4) {
      int h = hob2 + r; h = h < 112 ? h : 111;
      const signed char* src = xt + (((size_t)n * 112 + h) * 128 + wo_base) * 64;
      g2lds16(src + lane * 16, &Xs[r * ROWB]);
      g2lds16(src + 1024 + lane * 16, &Xs[r * ROWB + 1024]);
    }
    asm volatile("s_waitcnt vmcnt(0)" ::: "memory");
    __syncthreads();

    i32x4 acc[4];
    #pragma unroll
    for (int j = 0; j < 4; ++j) acc[j] = (i32x4){0, 0, 0, 0};

    i32x4 A0 = *(const i32x4*)(aB);
    i32x4 A1 = *(const i32x4*)(aB + (size_t)7 * WSLICE);
    i32x4 A2 = *(const i32x4*)(aB + (size_t)14 * WSLICE);

    kw_body_q<0>(0, aB, Xs, lrow, lkg, A0, A1, A2, acc);
    kw_body_q<1>(1, aB, Xs, lrow, lkg, A0, A1, A2, acc);
    kw_body_q<2>(2, aB, Xs, lrow, lkg, A0, A1, A2, acc);
    kw_body_q<0>(3, aB, Xs, lrow, lkg, A0, A1, A2, acc);
    kw_body_q<1>(4, aB, Xs, lrow, lkg, A0, A1, A2, acc);
    kw_body_q<2>(5, aB, Xs, lrow, lkg, A0, A1, A2, acc);
    kw_body_q<0>(6, aB, Xs, lrow, lkg, A0, A1, A2, acc);

    const int co  = coh * 64 + wid * 16 + lrow;
    const int wo0 = wo_base + lkg * 4;
    const bool full4 = (wo0 + 3) < 106;
    #pragma unroll
    for (int j = 0; j < 4; ++j) {
      const int ho = hob2 + j;
      if (ho < 106) {
        float* op = out + (((size_t)n * 128 + co) * 106 + ho) * 106 + wo0;
        if (full4) {
          *(f32x2*)(op)     = (f32x2){(float)acc[j][0], (float)acc[j][1]};
          *(f32x2*)(op + 2) = (f32x2){(float)acc[j][2], (float)acc[j][3]};
        } else {
          #pragma unroll
          for (int jj = 0; jj < 4; ++jj)
            if (wo0 + jj < 106) op[jj] = (float)acc[j][jj];
        }
      }
    }
  }
}

// ---- fallback (small ws): static grid 1568, stages straight from NCHW x
__global__ __launch_bounds__(256, 3)
void conv7f(const int* __restrict__ x,
            const signed char* __restrict__ wb, float* __restrict__ out) {
  __shared__ __align__(16) unsigned char Xs[XROWS * ROWB];

  const int tid  = threadIdx.x;
  const int lane = tid & 63;
  const int wid  = tid >> 6;
  const int lrow = lane & 15;
  const int lkg  = lane >> 4;

  const int L  = blockIdx.x;
  const int Lp = (L & 7) * 196 + (L >> 3);
  const int coh = Lp & 1;
  const int r2  = Lp >> 1;
  const int bx  = r2 % 7;
  const int t7  = r2 / 7;
  const int by  = t7 % 7;
  const int n   = t7 / 7;
  const int ho_base = by * 16;
  const int wo_base = bx * 16;

  const signed char* aB = wb + lkg * 2048 + coh * 1024 + lrow * 16;
  i32x4 A[4];
  #pragma unroll
  for (int m = 0; m < 4; ++m) A[m] = *(const i32x4*)(aB + m * 256);

  {
    const int w_a  = tid & 15,       cg_a  = tid >> 4;
    const int w_b2 = 16 + (tid & 7), cg_b2 = tid >> 3;
    const bool doB = (tid < 128) && ((tid & 7) < 6);
    const int keyA = ((w_a >> 1) & 3) << 2;
    const int keyB = ((w_b2 >> 1) & 3) << 2;
    for (int r = 0; r < XROWS; ++r) {
      int h = ho_base + r; h = h < 112 ? h : 111;
      const int* xr = x + (size_t)n * 64 * 12544 + h * 112;
      {
        int wc = wo_base + w_a; wc = wc < 112 ? wc : 111;
        uint32_t v = 0;
        #pragma unroll
        for (int j = 0; j < 4; ++j) {
          int a = xr[(cg_a * 4 + j) * 12544 + wc];
          a = a < 0 ? 0 : (a > 7 ? 7 : a);
          v |= (uint32_t)a << (8 * j);
        }
        *(uint32_t*)&Xs[r * ROWB + w_a * 64 + ((cg_a ^ keyA) << 2)] = v;
      }
      if (doB) {
        int wc = wo_base + w_b2; wc = wc < 112 ? wc : 111;
        uint32_t v = 0;
        #pragma unroll
        for (int j = 0; j < 4; ++j) {
          int a = xr[(cg_b2 * 4 + j) * 12544 + wc];
          a = a < 0 ? 0 : (a > 7 ? 7 : a);
          v |= (uint32_t)a << (8 * j);
        }
        *(uint32_t*)&Xs[r * ROWB + w_b2 * 64 + ((cg_b2 ^ keyB) << 2)] = v;
      }
    }
  }
  __syncthreads();

  i32x4 acc[4][4];
  #pragma unroll
  for (int m = 0; m < 4; ++m)
    #pragma unroll
    for (int b = 0; b < 4; ++b)
      acc[m][b] = (i32x4){0, 0, 0, 0};

  const int rowB = wid * 4;

  for (int kw = 0; kw < 7; ++kw) {
    const int w_l  = lrow + kw;
    const int bcol = w_l * 64 + ((lkg ^ ((w_l >> 1) & 3)) << 4);
    i32x4 B[8];
    #pragma unroll
    for (int b = 0; b < 4; ++b)
      B[b] = *(const i32x4*)&Xs[(rowB + b) * ROWB + bcol];
    #pragma unroll
    for (int kh = 0; kh < 7; ++kh) {
      if (kh < 6)
        B[(kh + 4) & 7] = *(const i32x4*)&Xs[(rowB + kh + 4) * ROWB + bcol];
      const signed char* apn = aB + (size_t)(kh < 6 ? (kh + 1) * 7 + kw : kw + 1) * WSLICE;
      #pragma unroll
      for (int m = 0; m < 4; ++m) {
        #pragma unroll
        for (int b = 0; b < 4; ++b)
          MFMA16(acc[m][b], A[m], B[(kh + b) & 7]);
        A[m] = *(const i32x4*)(apn + m * 256);
      }
    }
  }

  const int wo = wo_base + lrow;
  if (wo < 106) {
    #pragma unroll
    for (int m = 0; m < 4; ++m) {
      const int co = coh * 64 + m * 16 + lkg * 4;
      #pragma unroll
      for (int b = 0; b < 4; ++b) {
        const int ho = ho_base + rowB + b;
        if (ho < 106) {
          float* op = out + (((size_t)n * 128 + co) * 106 + ho) * 106 + wo;
          #pragma unroll
          for (int j = 0; j < 4; ++j)
            op[(size_t)j * 11236] = (float)acc[m][b][j];
        }
      }
    }
  }
}

extern "C" void kernel_launch(void* const* d_in, const int* in_sizes, int n_in,
                              void* d_out, int out_size, void* d_ws, size_t ws_size,
                              hipStream_t stream) {
  const int*   x  = (const int*)d_in[0];
  const float* w1 = (const float*)d_in[1];
  const float* w2 = (const float*)d_in[2];
  const float* w3 = (const float*)d_in[3];
  float* outp = (float*)d_out;
  signed char* wbp = (signed char*)d_ws;
  signed char* xtp = wbp + WB_BYTES;

  if (ws_size >= WB_BYTES + XT_BYTES) {
    prep_xw<<<dim3(2, 112, 16), dim3(256), 0, stream>>>(x, w1, w2, w3, xtp, wbp);
    conv7s<<<dim3(GRID_MAIN), dim3(256), 0, stream>>>(xtp, wbp, outp);
  } else {
    prep_w<<<dim3(1568), dim3(256), 0, stream>>>(w1, w2, w3, wbp);
    conv7f<<<dim3(1568), dim3(256), 0, stream>>>(x, wbp, outp);
  }
}

// Round 15
// 68.847 us; speedup vs baseline: 1.0108x; 1.0108x over previous
//
#include <hip/hip_runtime.h>
#include <cstdint>

typedef __attribute__((ext_vector_type(4))) int i32x4;

#define XROWS  22
#define ROWB   2048              // LDS bytes per staged row (w 0..31, 64B each)
#define WSLICE 8192
#define WB_BYTES 409600          // wb (401408) rounded up
#define XT_BYTES ((size_t)16 * 112 * 128 * 64)
#define GRID_MAIN 1536           // 2 exact layers at 3 blocks/CU; 128 blocks run a quarter-tile pass 2

__device__ __forceinline__ void g2lds16(const void* g, void* l) {
  __builtin_amdgcn_global_load_lds(
      (const __attribute__((address_space(1))) unsigned int*)g,
      (__attribute__((address_space(3))) unsigned int*)l, 16, 0, 0);
}

// ---- standalone W pack (fallback path): wb[((s*4+g)*128+co)*16+lo], s=kh*7+kw
__global__ void prep_w(const float* __restrict__ w1,
                       const float* __restrict__ w2,
                       const float* __restrict__ w3,
                       signed char* __restrict__ wb) {
  int t = blockIdx.x * 256 + threadIdx.x;
  int lo = t & 15;
  int co = (t >> 4) & 127;
  int g  = (t >> 11) & 3;
  int s  = t >> 13;
  if (s >= 49) return;
  int kh = s / 7, kw = s % 7;
  int ci = g * 16 + lo;
  int base = ((co * 64 + ci) * 7 + kh) * 3;
  float v;
  if (kw < 3)       v = w1[base + kw];
  else if (kw == 3) v = w2[base + 1];
  else              v = w3[base + kw - 4];
  wb[t] = (signed char)(int)v;
}

// ---- merged prep: X pre-transpose + W pack (16x16 layout).
// xt[n][h][w(128)][ci(64)] i8, clamped, 16B-granule-swizzled (granule p holds
// ci-granule p ^ ((w>>1)&3)).
__global__ void prep_xw(const int* __restrict__ x,
                        const float* __restrict__ w1,
                        const float* __restrict__ w2,
                        const float* __restrict__ w3,
                        signed char* __restrict__ xt,
                        signed char* __restrict__ wb) {
  __shared__ unsigned char T[64 * 68];
  const int tid = threadIdx.x;
  const int wt = blockIdx.x * 64, h = blockIdx.y, n = blockIdx.z;
  const int fid = (blockIdx.z * 112 + blockIdx.y) * 2 + blockIdx.x;

  if (fid < 1568) {                              // W pack: 1568*256 = 401408 elems
    int t = fid * 256 + tid;
    int lo = t & 15;
    int co = (t >> 4) & 127;
    int g  = (t >> 11) & 3;
    int s  = t >> 13;
    int kh = s / 7, kw = s % 7;
    int ci = g * 16 + lo;
    int base = ((co * 64 + ci) * 7 + kh) * 3;
    float v;
    if (kw < 3)       v = w1[base + kw];
    else if (kw == 3) v = w2[base + 1];
    else              v = w3[base + kw - 4];
    wb[t] = (signed char)(int)v;
  }

  {
    const int wr = tid & 63;
    const int cb = (tid >> 6) * 16;
    int ws = wt + wr; ws = ws < 112 ? ws : 111;
    const int* xp = x + (((size_t)n * 64 + cb) * 112 + h) * 112 + ws;
    #pragma unroll
    for (int g4 = 0; g4 < 4; ++g4) {
      uint32_t v = 0;
      #pragma unroll
      for (int j = 0; j < 4; ++j) {
        int a = xp[(g4 * 4 + j) * 12544];
        a = a < 0 ? 0 : (a > 7 ? 7 : a);
        v |= (uint32_t)a << (8 * j);
      }
      *(uint32_t*)&T[wr * 68 + cb + g4 * 4] = v;
    }
  }
  __syncthreads();
  {
    const int wo = tid >> 2, q = tid & 3;
    const int key = ((wt + wo) >> 1) & 3;
    const int sg = (q ^ key) << 4;
    int4 v;
    v.x = *(const int*)&T[wo * 68 + sg + 0];
    v.y = *(const int*)&T[wo * 68 + sg + 4];
    v.z = *(const int*)&T[wo * 68 + sg + 8];
    v.w = *(const int*)&T[wo * 68 + sg + 12];
    *(int4*)&xt[(((size_t)n * 112 + h) * 128 + wt + wo) * 64 + q * 16] = v;
  }
}

#define MFMA16(acc, a, b) acc = __builtin_amdgcn_mfma_i32_16x16x64_i8(a, b, acc, 0, 0, 0)

// One kw column: 16 B-ring reads, 7 kh batches of 16 MFMA.
// A-ring slot = (kh + PHASE) % 3, PHASE = position-in-sequence % 3.
// After batch kh retires its A, load slice c+3 in consumption order.
template<int PHASE>
__device__ __forceinline__ void kw_body(const int kw,
    const signed char* __restrict__ aB, const unsigned char* Xs,
    const int lrow, const int lkg,
    i32x4& A0, i32x4& A1, i32x4& A2, i32x4 (&acc)[16]) {
  const int w_l  = lrow + kw;
  const int bcol = w_l * 64 + ((lkg ^ ((w_l >> 1) & 3)) << 4);
  i32x4 B[16];                             // ring: slot r&15 holds row r
  #pragma unroll
  for (int b = 0; b < 16; ++b)
    B[b] = *(const i32x4*)&Xs[b * ROWB + bcol];

  #pragma unroll
  for (int kh = 0; kh < 7; ++kh) {
    // c+3 in rotated consumption order: (kh+3, kw) or (kh-4, (kw+1)%7); s = kh*7+kw
    const int nkh = (kh <= 3) ? kh + 3 : kh - 4;
    const int nkw = (kh <= 3) ? kw : (kw == 6 ? 0 : kw + 1);
    const signed char* apn = aB + (size_t)(nkh * 7 + nkw) * WSLICE;
    __builtin_amdgcn_s_setprio(1);
    if (((kh + PHASE) % 3) == 0) {
      MFMA16(acc[0], A0, B[kh]);                    // j=0: last consumer of slot kh
      if (kh < 6) B[kh] = *(const i32x4*)&Xs[(kh + 16) * ROWB + bcol];  // early refill
      #pragma unroll
      for (int j = 1; j < 16; ++j) MFMA16(acc[j], A0, B[(kh + j) & 15]);
      __builtin_amdgcn_s_setprio(0);
      A0 = *(const i32x4*)apn;                      // reload freed slot (slice c+3)
    } else if (((kh + PHASE) % 3) == 1) {
      MFMA16(acc[0], A1, B[kh]);
      if (kh < 6) B[kh] = *(const i32x4*)&Xs[(kh + 16) * ROWB + bcol];
      #pragma unroll
      for (int j = 1; j < 16; ++j) MFMA16(acc[j], A1, B[(kh + j) & 15]);
      __builtin_amdgcn_s_setprio(0);
      A1 = *(const i32x4*)apn;
    } else {
      MFMA16(acc[0], A2, B[kh]);
      if (kh < 6) B[kh] = *(const i32x4*)&Xs[(kh + 16) * ROWB + bcol];
      #pragma unroll
      for (int j = 1; j < 16; ++j) MFMA16(acc[j], A2, B[(kh + j) & 15]);
      __builtin_amdgcn_s_setprio(0);
      A2 = *(const i32x4*)apn;
    }
  }
}

// Quarter-tile column (pass 2 tail): 4 ho rows, B[10] flat, A-ring-3.
// Original operand order (A = W-frag, B = X-frag).
template<int PHASE>
__device__ __forceinline__ void kw_body_q(const int kw,
    const signed char* __restrict__ aB, const unsigned char* Xs,
    const int lrow, const int lkg,
    i32x4& A0, i32x4& A1, i32x4& A2, i32x4 (&acc)[4]) {
  const int w_l  = lrow + kw;
  const int bcol = w_l * 64 + ((lkg ^ ((w_l >> 1) & 3)) << 4);
  i32x4 B[10];
  #pragma unroll
  for (int b = 0; b < 10; ++b)
    B[b] = *(const i32x4*)&Xs[b * ROWB + bcol];
  #pragma unroll
  for (int kh = 0; kh < 7; ++kh) {
    const int nkh = (kh <= 3) ? kh + 3 : kh - 4;
    const int nkw = (kh <= 3) ? kw : (kw == 6 ? 0 : kw + 1);
    const signed char* apn = aB + (size_t)(nkh * 7 + nkw) * WSLICE;
    if (((kh + PHASE) % 3) == 0) {
      #pragma unroll
      for (int j = 0; j < 4; ++j) MFMA16(acc[j], A0, B[kh + j]);
      A0 = *(const i32x4*)apn;
    } else if (((kh + PHASE) % 3) == 1) {
      #pragma unroll
      for (int j = 0; j < 4; ++j) MFMA16(acc[j], A1, B[kh + j]);
      A1 = *(const i32x4*)apn;
    } else {
      #pragma unroll
      for (int j = 0; j < 4; ++j) MFMA16(acc[j], A2, B[kh + j]);
      A2 = *(const i32x4*)apn;
    }
  }
}

// ---- main conv: static grid 1536; blocks 0..127 run one ho-quarter of the
// 32 leftover tiles as pass 2 (tail runs 128-wide instead of 32-solo).
// Wave = co16 x ho16 x wo16; original epilogue map (lanes -> consecutive wo).
__global__ __launch_bounds__(256, 3)
void conv7s(const signed char* __restrict__ xt,
            const signed char* __restrict__ wb,
            float* __restrict__ out) {
  __shared__ __align__(16) unsigned char Xs[XROWS * ROWB];   // 45056 B

  const int tid  = threadIdx.x;
  const int lane = tid & 63;
  const int wid  = tid >> 6;               // wave = co16 quarter of co64
  const int lrow = lane & 15;
  const int lkg  = lane >> 4;

  // bijective XCD chunking: 1536 = 8 * 192
  const int L  = blockIdx.x;
  const int Lp = (L & 7) * 192 + (L >> 3);

  // rotated kw sequence (any order exact for int accum; desync across blocks)
  const int k0 = (L >> 3) % 7;
  const int k1 = (k0 + 1) % 7;
  const int k2 = (k0 + 2) % 7;
  const int k3 = (k0 + 3) % 7;
  const int k4 = (k0 + 4) % 7;
  const int k5 = (k0 + 5) % 7;
  const int k6 = (k0 + 6) % 7;

  // ================= pass 1: full tile =================
  {
    const int t = Lp;
    const int coh = t & 1;
    const int r2  = t >> 1;
    const int bx  = r2 % 7;
    const int t7  = r2 / 7;
    const int by  = t7 % 7;
    const int n   = t7 / 7;
    const int ho_base = by * 16;
    const int wo_base = bx * 16;

    // A-frag base: wb addr = s*8192 + g*2048 + co*16; co = coh*64 + wid*16 + lrow
    const signed char* aB = wb + lkg * 2048 + (coh * 64 + wid * 16 + lrow) * 16;

    // A-ring prologue: slices (kh,kw) = (0,k0),(1,k0),(2,k0) -> slots 0,1,2
    i32x4 A0 = *(const i32x4*)(aB + (size_t)(0 * 7 + k0) * WSLICE);
    i32x4 A1 = *(const i32x4*)(aB + (size_t)(1 * 7 + k0) * WSLICE);
    i32x4 A2 = *(const i32x4*)(aB + (size_t)(2 * 7 + k0) * WSLICE);

    for (int r = wid; r < XROWS; r += 4) {
      int h = ho_base + r; h = h < 112 ? h : 111;   // clamped rows feed only masked outputs
      const signed char* src = xt + (((size_t)n * 112 + h) * 128 + wo_base) * 64;
      g2lds16(src + lane * 16, &Xs[r * ROWB]);
      g2lds16(src + 1024 + lane * 16, &Xs[r * ROWB + 1024]);
    }
    asm volatile("s_waitcnt vmcnt(0)" ::: "memory");
    __syncthreads();

    i32x4 acc[16];
    #pragma unroll
    for (int j = 0; j < 16; ++j) acc[j] = (i32x4){0, 0, 0, 0};

    kw_body<0>(k0, aB, Xs, lrow, lkg, A0, A1, A2, acc);
    kw_body<1>(k1, aB, Xs, lrow, lkg, A0, A1, A2, acc);
    kw_body<2>(k2, aB, Xs, lrow, lkg, A0, A1, A2, acc);
    kw_body<0>(k3, aB, Xs, lrow, lkg, A0, A1, A2, acc);
    kw_body<1>(k4, aB, Xs, lrow, lkg, A0, A1, A2, acc);
    kw_body<2>(k5, aB, Xs, lrow, lkg, A0, A1, A2, acc);
    kw_body<0>(k6, aB, Xs, lrow, lkg, A0, A1, A2, acc);

    // epilogue: C/D map col=lane&15 (wo), row=(lane>>4)*4+jj (co); i32->f32 exact
    const int wo = wo_base + lrow;
    if (wo < 106) {
      const int co = coh * 64 + wid * 16 + lkg * 4;
      #pragma unroll
      for (int j = 0; j < 16; ++j) {
        const int ho = ho_base + j;
        if (ho < 106) {
          float* op = out + (((size_t)n * 128 + co) * 106 + ho) * 106 + wo;
          #pragma unroll
          for (int jj = 0; jj < 4; ++jj)
            op[(size_t)jj * 11236] = (float)acc[j][jj];
        }
      }
    }
  }

  // ================= pass 2: quarter tile (tail) =================
  if (L < 128) {
    const int t = GRID_MAIN + (L >> 2);    // tiles 1536..1567
    const int q = L & 3;                   // ho quarter
    const int coh = t & 1;
    const int r2  = t >> 1;
    const int bx  = r2 % 7;
    const int t7  = r2 / 7;
    const int by  = t7 % 7;
    const int n   = t7 / 7;
    const int hob2    = by * 16 + q * 4;
    const int wo_base = bx * 16;

    const signed char* aB = wb + lkg * 2048 + (coh * 64 + wid * 16 + lrow) * 16;

    __syncthreads();                       // protect Xs reuse
    for (int r = wid; r < 10; r += 4) {
      int h = hob2 + r; h = h < 112 ? h : 111;
      const signed char* src = xt + (((size_t)n * 112 + h) * 128 + wo_base) * 64;
      g2lds16(src + lane * 16, &Xs[r * ROWB]);
      g2lds16(src + 1024 + lane * 16, &Xs[r * ROWB + 1024]);
    }
    asm volatile("s_waitcnt vmcnt(0)" ::: "memory");
    __syncthreads();

    i32x4 acc[4];
    #pragma unroll
    for (int j = 0; j < 4; ++j) acc[j] = (i32x4){0, 0, 0, 0};

    i32x4 A0 = *(const i32x4*)(aB);
    i32x4 A1 = *(const i32x4*)(aB + (size_t)7 * WSLICE);
    i32x4 A2 = *(const i32x4*)(aB + (size_t)14 * WSLICE);

    kw_body_q<0>(0, aB, Xs, lrow, lkg, A0, A1, A2, acc);
    kw_body_q<1>(1, aB, Xs, lrow, lkg, A0, A1, A2, acc);
    kw_body_q<2>(2, aB, Xs, lrow, lkg, A0, A1, A2, acc);
    kw_body_q<0>(3, aB, Xs, lrow, lkg, A0, A1, A2, acc);
    kw_body_q<1>(4, aB, Xs, lrow, lkg, A0, A1, A2, acc);
    kw_body_q<2>(5, aB, Xs, lrow, lkg, A0, A1, A2, acc);
    kw_body_q<0>(6, aB, Xs, lrow, lkg, A0, A1, A2, acc);

    const int wo = wo_base + lrow;
    if (wo < 106) {
      const int co = coh * 64 + wid * 16 + lkg * 4;
      #pragma unroll
      for (int j = 0; j < 4; ++j) {
        const int ho = hob2 + j;
        if (ho < 106) {
          float* op = out + (((size_t)n * 128 + co) * 106 + ho) * 106 + wo;
          #pragma unroll
          for (int jj = 0; jj < 4; ++jj)
            op[(size_t)jj * 11236] = (float)acc[j][jj];
        }
      }
    }
  }
}

// ---- fallback (small ws): static grid 1568, stages straight from NCHW x
__global__ __launch_bounds__(256, 3)
void conv7f(const int* __restrict__ x,
            const signed char* __restrict__ wb, float* __restrict__ out) {
  __shared__ __align__(16) unsigned char Xs[XROWS * ROWB];

  const int tid  = threadIdx.x;
  const int lane = tid & 63;
  const int wid  = tid >> 6;
  const int lrow = lane & 15;
  const int lkg  = lane >> 4;

  const int L  = blockIdx.x;
  const int Lp = (L & 7) * 196 + (L >> 3);
  const int coh = Lp & 1;
  const int r2  = Lp >> 1;
  const int bx  = r2 % 7;
  const int t7  = r2 / 7;
  const int by  = t7 % 7;
  const int n   = t7 / 7;
  const int ho_base = by * 16;
  const int wo_base = bx * 16;

  const signed char* aB = wb + lkg * 2048 + coh * 1024 + lrow * 16;
  i32x4 A[4];
  #pragma unroll
  for (int m = 0; m < 4; ++m) A[m] = *(const i32x4*)(aB + m * 256);

  {
    const int w_a  = tid & 15,       cg_a  = tid >> 4;
    const int w_b2 = 16 + (tid & 7), cg_b2 = tid >> 3;
    const bool doB = (tid < 128) && ((tid & 7) < 6);
    const int keyA = ((w_a >> 1) & 3) << 2;
    const int keyB = ((w_b2 >> 1) & 3) << 2;
    for (int r = 0; r < XROWS; ++r) {
      int h = ho_base + r; h = h < 112 ? h : 111;
      const int* xr = x + (size_t)n * 64 * 12544 + h * 112;
      {
        int wc = wo_base + w_a; wc = wc < 112 ? wc : 111;
        uint32_t v = 0;
        #pragma unroll
        for (int j = 0; j < 4; ++j) {
          int a = xr[(cg_a * 4 + j) * 12544 + wc];
          a = a < 0 ? 0 : (a > 7 ? 7 : a);
          v |= (uint32_t)a << (8 * j);
        }
        *(uint32_t*)&Xs[r * ROWB + w_a * 64 + ((cg_a ^ keyA) << 2)] = v;
      }
      if (doB) {
        int wc = wo_base + w_b2; wc = wc < 112 ? wc : 111;
        uint32_t v = 0;
        #pragma unroll
        for (int j = 0; j < 4; ++j) {
          int a = xr[(cg_b2 * 4 + j) * 12544 + wc];
          a = a < 0 ? 0 : (a > 7 ? 7 : a);
          v |= (uint32_t)a << (8 * j);
        }
        *(uint32_t*)&Xs[r * ROWB + w_b2 * 64 + ((cg_b2 ^ keyB) << 2)] = v;
      }
    }
  }
  __syncthreads();

  i32x4 acc[4][4];
  #pragma unroll
  for (int m = 0; m < 4; ++m)
    #pragma unroll
    for (int b = 0; b < 4; ++b)
      acc[m][b] = (i32x4){0, 0, 0, 0};

  const int rowB = wid * 4;

  for (int kw = 0; kw < 7; ++kw) {
    const int w_l  = lrow + kw;
    const int bcol = w_l * 64 + ((lkg ^ ((w_l >> 1) & 3)) << 4);
    i32x4 B[8];
    #pragma unroll
    for (int b = 0; b < 4; ++b)
      B[b] = *(const i32x4*)&Xs[(rowB + b) * ROWB + bcol];
    #pragma unroll
    for (int kh = 0; kh < 7; ++kh) {
      if (kh < 6)
        B[(kh + 4) & 7] = *(const i32x4*)&Xs[(rowB + kh + 4) * ROWB + bcol];
      const signed char* apn = aB + (size_t)(kh < 6 ? (kh + 1) * 7 + kw : kw + 1) * WSLICE;
      #pragma unroll
      for (int m = 0; m < 4; ++m) {
        #pragma unroll
        for (int b = 0; b < 4; ++b)
          MFMA16(acc[m][b], A[m], B[(kh + b) & 7]);
        A[m] = *(const i32x4*)(apn + m * 256);
      }
    }
  }

  const int wo = wo_base + lrow;
  if (wo < 106) {
    #pragma unroll
    for (int m = 0; m < 4; ++m) {
      const int co = coh * 64 + m * 16 + lkg * 4;
      #pragma unroll
      for (int b = 0; b < 4; ++b) {
        const int ho = ho_base + rowB + b;
        if (ho < 106) {
          float* op = out + (((size_t)n * 128 + co) * 106 + ho) * 106 + wo;
          #pragma unroll
          for (int j = 0; j < 4; ++j)
            op[(size_t)j * 11236] = (float)acc[m][b][j];
        }
      }
    }
  }
}

extern "C" void kernel_launch(void* const* d_in, const int* in_sizes, int n_in,
                              void* d_out, int out_size, void* d_ws, size_t ws_size,
                              hipStream_t stream) {
  const int*   x  = (const int*)d_in[0];
  const float* w1 = (const float*)d_in[1];
  const float* w2 = (const float*)d_in[2];
  const float* w3 = (const float*)d_in[3];
  float* outp = (float*)d_out;
  signed char* wbp = (signed char*)d_ws;
  signed char* xtp = wbp + WB_BYTES;

  if (ws_size >= WB_BYTES + XT_BYTES) {
    prep_xw<<<dim3(2, 112, 16), dim3(256), 0, stream>>>(x, w1, w2, w3, xtp, wbp);
    conv7s<<<dim3(GRID_MAIN), dim3(256), 0, stream>>>(xtp, wbp, outp);
  } else {
    prep_w<<<dim3(1568), dim3(256), 0, stream>>>(w1, w2, w3, wbp);
    conv7f<<<dim3(1568), dim3(256), 0, stream>>>(x, wbp, outp);
  }
}

// Round 16
// 67.838 us; speedup vs baseline: 1.0258x; 1.0149x over previous
//
#include <hip/hip_runtime.h>
#include <cstdint>

typedef __attribute__((ext_vector_type(4))) int i32x4;

#define XROWS  22
#define ROWB   2048              // LDS bytes per staged row (w 0..31, 64B each)
#define WSLICE 8192
#define WB_BYTES 409600          // wb (401408) rounded up
#define XT_BYTES ((size_t)16 * 112 * 128 * 64)
#define GRID_MAIN 1536           // 2 exact layers at 3 blocks/CU; 128 blocks run a quarter-tile pass 2

__device__ __forceinline__ void g2lds16(const void* g, void* l) {
  __builtin_amdgcn_global_load_lds(
      (const __attribute__((address_space(1))) unsigned int*)g,
      (__attribute__((address_space(3))) unsigned int*)l, 16, 0, 0);
}

// ---- standalone W pack (fallback path): wb[((s*4+g)*128+co)*16+lo], s=kh*7+kw
__global__ void prep_w(const float* __restrict__ w1,
                       const float* __restrict__ w2,
                       const float* __restrict__ w3,
                       signed char* __restrict__ wb) {
  int t = blockIdx.x * 256 + threadIdx.x;
  int lo = t & 15;
  int co = (t >> 4) & 127;
  int g  = (t >> 11) & 3;
  int s  = t >> 13;
  if (s >= 49) return;
  int kh = s / 7, kw = s % 7;
  int ci = g * 16 + lo;
  int base = ((co * 64 + ci) * 7 + kh) * 3;
  float v;
  if (kw < 3)       v = w1[base + kw];
  else if (kw == 3) v = w2[base + 1];
  else              v = w3[base + kw - 4];
  wb[t] = (signed char)(int)v;
}

// ---- merged prep: X pre-transpose + W pack (16x16 layout).
// xt[n][h][w(128)][ci(64)] i8, clamped, 16B-granule-swizzled (granule p holds
// ci-granule p ^ ((w>>1)&3)).
__global__ void prep_xw(const int* __restrict__ x,
                        const float* __restrict__ w1,
                        const float* __restrict__ w2,
                        const float* __restrict__ w3,
                        signed char* __restrict__ xt,
                        signed char* __restrict__ wb) {
  __shared__ unsigned char T[64 * 68];
  const int tid = threadIdx.x;
  const int wt = blockIdx.x * 64, h = blockIdx.y, n = blockIdx.z;
  const int fid = (blockIdx.z * 112 + blockIdx.y) * 2 + blockIdx.x;

  if (fid < 1568) {                              // W pack: 1568*256 = 401408 elems
    int t = fid * 256 + tid;
    int lo = t & 15;
    int co = (t >> 4) & 127;
    int g  = (t >> 11) & 3;
    int s  = t >> 13;
    int kh = s / 7, kw = s % 7;
    int ci = g * 16 + lo;
    int base = ((co * 64 + ci) * 7 + kh) * 3;
    float v;
    if (kw < 3)       v = w1[base + kw];
    else if (kw == 3) v = w2[base + 1];
    else              v = w3[base + kw - 4];
    wb[t] = (signed char)(int)v;
  }

  {
    const int wr = tid & 63;
    const int cb = (tid >> 6) * 16;
    int ws = wt + wr; ws = ws < 112 ? ws : 111;
    const int* xp = x + (((size_t)n * 64 + cb) * 112 + h) * 112 + ws;
    #pragma unroll
    for (int g4 = 0; g4 < 4; ++g4) {
      uint32_t v = 0;
      #pragma unroll
      for (int j = 0; j < 4; ++j) {
        int a = xp[(g4 * 4 + j) * 12544];
        a = a < 0 ? 0 : (a > 7 ? 7 : a);
        v |= (uint32_t)a << (8 * j);
      }
      *(uint32_t*)&T[wr * 68 + cb + g4 * 4] = v;
    }
  }
  __syncthreads();
  {
    const int wo = tid >> 2, q = tid & 3;
    const int key = ((wt + wo) >> 1) & 3;
    const int sg = (q ^ key) << 4;
    int4 v;
    v.x = *(const int*)&T[wo * 68 + sg + 0];
    v.y = *(const int*)&T[wo * 68 + sg + 4];
    v.z = *(const int*)&T[wo * 68 + sg + 8];
    v.w = *(const int*)&T[wo * 68 + sg + 12];
    *(int4*)&xt[(((size_t)n * 112 + h) * 128 + wt + wo) * 64 + q * 16] = v;
  }
}

#define MFMA16(acc, a, b) acc = __builtin_amdgcn_mfma_i32_16x16x64_i8(a, b, acc, 0, 0, 0)

// One kw column (kw = KW, compile-time): 16 B-ring reads, 7 kh batches of 16 MFMA.
// All B addresses fold to ds_read offset immediates off a per-tile bcol; all
// A-prefetch deltas are wave-uniform constants. A-ring slot = (kh + KW) % 3.
template<int KW>
__device__ __forceinline__ void kw_body(
    const signed char* __restrict__ aB, const unsigned char* Xs,
    const int lrow, const int lkg,
    i32x4& A0, i32x4& A1, i32x4& A2, i32x4 (&acc)[16]) {
  const int w_l  = lrow + KW;
  const int bcol = w_l * 64 + ((lkg ^ ((w_l >> 1) & 3)) << 4);
  i32x4 B[16];                             // ring: slot r&15 holds row r
  #pragma unroll
  for (int b = 0; b < 16; ++b)
    B[b] = *(const i32x4*)&Xs[b * ROWB + bcol];

  #pragma unroll
  for (int kh = 0; kh < 7; ++kh) {
    // consumption c = KW*7 + kh; c+3: (kh+3, KW) or (kh-4, KW+1 mod 7)
    const int nkh = (kh <= 3) ? kh + 3 : kh - 4;
    const int nkw = (kh <= 3) ? KW : (KW == 6 ? 0 : KW + 1);
    const signed char* apn = aB + (size_t)(nkh * 7 + nkw) * WSLICE;
    __builtin_amdgcn_s_setprio(1);
    if (((kh + KW) % 3) == 0) {
      MFMA16(acc[0], A0, B[kh]);                    // j=0: last consumer of slot kh
      if (kh < 6) B[kh] = *(const i32x4*)&Xs[(kh + 16) * ROWB + bcol];  // early refill
      #pragma unroll
      for (int j = 1; j < 16; ++j) MFMA16(acc[j], A0, B[(kh + j) & 15]);
      __builtin_amdgcn_s_setprio(0);
      A0 = *(const i32x4*)apn;                      // reload freed slot (slice c+3)
    } else if (((kh + KW) % 3) == 1) {
      MFMA16(acc[0], A1, B[kh]);
      if (kh < 6) B[kh] = *(const i32x4*)&Xs[(kh + 16) * ROWB + bcol];
      #pragma unroll
      for (int j = 1; j < 16; ++j) MFMA16(acc[j], A1, B[(kh + j) & 15]);
      __builtin_amdgcn_s_setprio(0);
      A1 = *(const i32x4*)apn;
    } else {
      MFMA16(acc[0], A2, B[kh]);
      if (kh < 6) B[kh] = *(const i32x4*)&Xs[(kh + 16) * ROWB + bcol];
      #pragma unroll
      for (int j = 1; j < 16; ++j) MFMA16(acc[j], A2, B[(kh + j) & 15]);
      __builtin_amdgcn_s_setprio(0);
      A2 = *(const i32x4*)apn;
    }
  }
}

// Quarter-tile column (pass 2 tail): 4 ho rows, B[10] flat, A-ring-3.
template<int KW>
__device__ __forceinline__ void kw_body_q(
    const signed char* __restrict__ aB, const unsigned char* Xs,
    const int lrow, const int lkg,
    i32x4& A0, i32x4& A1, i32x4& A2, i32x4 (&acc)[4]) {
  const int w_l  = lrow + KW;
  const int bcol = w_l * 64 + ((lkg ^ ((w_l >> 1) & 3)) << 4);
  i32x4 B[10];
  #pragma unroll
  for (int b = 0; b < 10; ++b)
    B[b] = *(const i32x4*)&Xs[b * ROWB + bcol];
  #pragma unroll
  for (int kh = 0; kh < 7; ++kh) {
    const int nkh = (kh <= 3) ? kh + 3 : kh - 4;
    const int nkw = (kh <= 3) ? KW : (KW == 6 ? 0 : KW + 1);
    const signed char* apn = aB + (size_t)(nkh * 7 + nkw) * WSLICE;
    if (((kh + KW) % 3) == 0) {
      #pragma unroll
      for (int j = 0; j < 4; ++j) MFMA16(acc[j], A0, B[kh + j]);
      A0 = *(const i32x4*)apn;
    } else if (((kh + KW) % 3) == 1) {
      #pragma unroll
      for (int j = 0; j < 4; ++j) MFMA16(acc[j], A1, B[kh + j]);
      A1 = *(const i32x4*)apn;
    } else {
      #pragma unroll
      for (int j = 0; j < 4; ++j) MFMA16(acc[j], A2, B[kh + j]);
      A2 = *(const i32x4*)apn;
    }
  }
}

// ---- main conv: static grid 1536; blocks 0..127 run one ho-quarter of the
// 32 leftover tiles as pass 2. Wave = co16 x ho16 x wo16; compile-time kw.
__global__ __launch_bounds__(256, 3)
void conv7s(const signed char* __restrict__ xt,
            const signed char* __restrict__ wb,
            float* __restrict__ out) {
  __shared__ __align__(16) unsigned char Xs[XROWS * ROWB];   // 45056 B

  const int tid  = threadIdx.x;
  const int lane = tid & 63;
  const int wid  = tid >> 6;               // wave = co16 quarter of co64
  const int lrow = lane & 15;
  const int lkg  = lane >> 4;

  // bijective XCD chunking: 1536 = 8 * 192
  const int L  = blockIdx.x;
  const int Lp = (L & 7) * 192 + (L >> 3);

  // ================= pass 1: full tile =================
  {
    const int t = Lp;
    const int coh = t & 1;
    const int r2  = t >> 1;
    const int bx  = r2 % 7;
    const int t7  = r2 / 7;
    const int by  = t7 % 7;
    const int n   = t7 / 7;
    const int ho_base = by * 16;
    const int wo_base = bx * 16;

    // A-frag base: wb addr = s*8192 + g*2048 + co*16; co = coh*64 + wid*16 + lrow
    const signed char* aB = wb + lkg * 2048 + (coh * 64 + wid * 16 + lrow) * 16;

    // A-ring prologue: slices (kh,kw) = (0,0),(1,0),(2,0) -> slots 0,1,2
    i32x4 A0 = *(const i32x4*)(aB);
    i32x4 A1 = *(const i32x4*)(aB + (size_t)7 * WSLICE);
    i32x4 A2 = *(const i32x4*)(aB + (size_t)14 * WSLICE);

    for (int r = wid; r < XROWS; r += 4) {
      int h = ho_base + r; h = h < 112 ? h : 111;   // clamped rows feed only masked outputs
      const signed char* src = xt + (((size_t)n * 112 + h) * 128 + wo_base) * 64;
      g2lds16(src + lane * 16, &Xs[r * ROWB]);
      g2lds16(src + 1024 + lane * 16, &Xs[r * ROWB + 1024]);
    }
    asm volatile("s_waitcnt vmcnt(0)" ::: "memory");
    __syncthreads();

    i32x4 acc[16];
    #pragma unroll
    for (int j = 0; j < 16; ++j) acc[j] = (i32x4){0, 0, 0, 0};

    kw_body<0>(aB, Xs, lrow, lkg, A0, A1, A2, acc);
    kw_body<1>(aB, Xs, lrow, lkg, A0, A1, A2, acc);
    kw_body<2>(aB, Xs, lrow, lkg, A0, A1, A2, acc);
    kw_body<3>(aB, Xs, lrow, lkg, A0, A1, A2, acc);
    kw_body<4>(aB, Xs, lrow, lkg, A0, A1, A2, acc);
    kw_body<5>(aB, Xs, lrow, lkg, A0, A1, A2, acc);
    kw_body<6>(aB, Xs, lrow, lkg, A0, A1, A2, acc);

    // epilogue: C/D map col=lane&15 (wo), row=(lane>>4)*4+jj (co); i32->f32 exact
    const int wo = wo_base + lrow;
    if (wo < 106) {
      const int co = coh * 64 + wid * 16 + lkg * 4;
      #pragma unroll
      for (int j = 0; j < 16; ++j) {
        const int ho = ho_base + j;
        if (ho < 106) {
          float* op = out + (((size_t)n * 128 + co) * 106 + ho) * 106 + wo;
          #pragma unroll
          for (int jj = 0; jj < 4; ++jj)
            op[(size_t)jj * 11236] = (float)acc[j][jj];
        }
      }
    }
  }

  // ================= pass 2: quarter tile (tail) =================
  if (L < 128) {
    const int t = GRID_MAIN + (L >> 2);    // tiles 1536..1567
    const int q = L & 3;                   // ho quarter
    const int coh = t & 1;
    const int r2  = t >> 1;
    const int bx  = r2 % 7;
    const int t7  = r2 / 7;
    const int by  = t7 % 7;
    const int n   = t7 / 7;
    const int hob2    = by * 16 + q * 4;
    const int wo_base = bx * 16;

    const signed char* aB = wb + lkg * 2048 + (coh * 64 + wid * 16 + lrow) * 16;

    __syncthreads();                       // protect Xs reuse
    for (int r = wid; r < 10; r += 4) {
      int h = hob2 + r; h = h < 112 ? h : 111;
      const signed char* src = xt + (((size_t)n * 112 + h) * 128 + wo_base) * 64;
      g2lds16(src + lane * 16, &Xs[r * ROWB]);
      g2lds16(src + 1024 + lane * 16, &Xs[r * ROWB + 1024]);
    }
    asm volatile("s_waitcnt vmcnt(0)" ::: "memory");
    __syncthreads();

    i32x4 acc[4];
    #pragma unroll
    for (int j = 0; j < 4; ++j) acc[j] = (i32x4){0, 0, 0, 0};

    i32x4 A0 = *(const i32x4*)(aB);
    i32x4 A1 = *(const i32x4*)(aB + (size_t)7 * WSLICE);
    i32x4 A2 = *(const i32x4*)(aB + (size_t)14 * WSLICE);

    kw_body_q<0>(aB, Xs, lrow, lkg, A0, A1, A2, acc);
    kw_body_q<1>(aB, Xs, lrow, lkg, A0, A1, A2, acc);
    kw_body_q<2>(aB, Xs, lrow, lkg, A0, A1, A2, acc);
    kw_body_q<3>(aB, Xs, lrow, lkg, A0, A1, A2, acc);
    kw_body_q<4>(aB, Xs, lrow, lkg, A0, A1, A2, acc);
    kw_body_q<5>(aB, Xs, lrow, lkg, A0, A1, A2, acc);
    kw_body_q<6>(aB, Xs, lrow, lkg, A0, A1, A2, acc);

    const int wo = wo_base + lrow;
    if (wo < 106) {
      const int co = coh * 64 + wid * 16 + lkg * 4;
      #pragma unroll
      for (int j = 0; j < 4; ++j) {
        const int ho = hob2 + j;
        if (ho < 106) {
          float* op = out + (((size_t)n * 128 + co) * 106 + ho) * 106 + wo;
          #pragma unroll
          for (int jj = 0; jj < 4; ++jj)
            op[(size_t)jj * 11236] = (float)acc[j][jj];
        }
      }
    }
  }
}

// ---- fallback (small ws): static grid 1568, stages straight from NCHW x
__global__ __launch_bounds__(256, 3)
void conv7f(const int* __restrict__ x,
            const signed char* __restrict__ wb, float* __restrict__ out) {
  __shared__ __align__(16) unsigned char Xs[XROWS * ROWB];

  const int tid  = threadIdx.x;
  const int lane = tid & 63;
  const int wid  = tid >> 6;
  const int lrow = lane & 15;
  const int lkg  = lane >> 4;

  const int L  = blockIdx.x;
  const int Lp = (L & 7) * 196 + (L >> 3);
  const int coh = Lp & 1;
  const int r2  = Lp >> 1;
  const int bx  = r2 % 7;
  const int t7  = r2 / 7;
  const int by  = t7 % 7;
  const int n   = t7 / 7;
  const int ho_base = by * 16;
  const int wo_base = bx * 16;

  const signed char* aB = wb + lkg * 2048 + coh * 1024 + lrow * 16;
  i32x4 A[4];
  #pragma unroll
  for (int m = 0; m < 4; ++m) A[m] = *(const i32x4*)(aB + m * 256);

  {
    const int w_a  = tid & 15,       cg_a  = tid >> 4;
    const int w_b2 = 16 + (tid & 7), cg_b2 = tid >> 3;
    const bool doB = (tid < 128) && ((tid & 7) < 6);
    const int keyA = ((w_a >> 1) & 3) << 2;
    const int keyB = ((w_b2 >> 1) & 3) << 2;
    for (int r = 0; r < XROWS; ++r) {
      int h = ho_base + r; h = h < 112 ? h : 111;
      const int* xr = x + (size_t)n * 64 * 12544 + h * 112;
      {
        int wc = wo_base + w_a; wc = wc < 112 ? wc : 111;
        uint32_t v = 0;
        #pragma unroll
        for (int j = 0; j < 4; ++j) {
          int a = xr[(cg_a * 4 + j) * 12544 + wc];
          a = a < 0 ? 0 : (a > 7 ? 7 : a);
          v |= (uint32_t)a << (8 * j);
        }
        *(uint32_t*)&Xs[r * ROWB + w_a * 64 + ((cg_a ^ keyA) << 2)] = v;
      }
      if (doB) {
        int wc = wo_base + w_b2; wc = wc < 112 ? wc : 111;
        uint32_t v = 0;
        #pragma unroll
        for (int j = 0; j < 4; ++j) {
          int a = xr[(cg_b2 * 4 + j) * 12544 + wc];
          a = a < 0 ? 0 : (a > 7 ? 7 : a);
          v |= (uint32_t)a << (8 * j);
        }
        *(uint32_t*)&Xs[r * ROWB + w_b2 * 64 + ((cg_b2 ^ keyB) << 2)] = v;
      }
    }
  }
  __syncthreads();

  i32x4 acc[4][4];
  #pragma unroll
  for (int m = 0; m < 4; ++m)
    #pragma unroll
    for (int b = 0; b < 4; ++b)
      acc[m][b] = (i32x4){0, 0, 0, 0};

  const int rowB = wid * 4;

  for (int kw = 0; kw < 7; ++kw) {
    const int w_l  = lrow + kw;
    const int bcol = w_l * 64 + ((lkg ^ ((w_l >> 1) & 3)) << 4);
    i32x4 B[8];
    #pragma unroll
    for (int b = 0; b < 4; ++b)
      B[b] = *(const i32x4*)&Xs[(rowB + b) * ROWB + bcol];
    #pragma unroll
    for (int kh = 0; kh < 7; ++kh) {
      if (kh < 6)
        B[(kh + 4) & 7] = *(const i32x4*)&Xs[(rowB + kh + 4) * ROWB + bcol];
      const signed char* apn = aB + (size_t)(kh < 6 ? (kh + 1) * 7 + kw : kw + 1) * WSLICE;
      #pragma unroll
      for (int m = 0; m < 4; ++m) {
        #pragma unroll
        for (int b = 0; b < 4; ++b)
          MFMA16(acc[m][b], A[m], B[(kh + b) & 7]);
        A[m] = *(const i32x4*)(apn + m * 256);
      }
    }
  }

  const int wo = wo_base + lrow;
  if (wo < 106) {
    #pragma unroll
    for (int m = 0; m < 4; ++m) {
      const int co = coh * 64 + m * 16 + lkg * 4;
      #pragma unroll
      for (int b = 0; b < 4; ++b) {
        const int ho = ho_base + rowB + b;
        if (ho < 106) {
          float* op = out + (((size_t)n * 128 + co) * 106 + ho) * 106 + wo;
          #pragma unroll
          for (int j = 0; j < 4; ++j)
            op[(size_t)j * 11236] = (float)acc[m][b][j];
        }
      }
    }
  }
}

extern "C" void kernel_launch(void* const* d_in, const int* in_sizes, int n_in,
                              void* d_out, int out_size, void* d_ws, size_t ws_size,
                              hipStream_t stream) {
  const int*   x  = (const int*)d_in[0];
  const float* w1 = (const float*)d_in[1];
  const float* w2 = (const float*)d_in[2];
  const float* w3 = (const float*)d_in[3];
  float* outp = (float*)d_out;
  signed char* wbp = (signed char*)d_ws;
  signed char* xtp = wbp + WB_BYTES;

  if (ws_size >= WB_BYTES + XT_BYTES) {
    prep_xw<<<dim3(2, 112, 16), dim3(256), 0, stream>>>(x, w1, w2, w3, xtp, wbp);
    conv7s<<<dim3(GRID_MAIN), dim3(256), 0, stream>>>(xtp, wbp, outp);
  } else {
    prep_w<<<dim3(1568), dim3(256), 0, stream>>>(w1, w2, w3, wbp);
    conv7f<<<dim3(1568), dim3(256), 0, stream>>>(x, wbp, outp);
  }
}